// Round 4
// baseline (82.535 us; speedup 1.0000x reference)
//
#include <hip/hip_runtime.h>
#include <hip/hip_bf16.h>
#include <stdint.h>

#define BB 8
#define SS 8192
#define NN 16
#define DD 64
#define MM 64
#define TS 32    // s-rows per LDS tile
#define PAD 40   // row stride (bf16): 80 B -> every row 16B-aligned, 4 data octets + 1 pad

typedef __attribute__((ext_vector_type(8))) short bf16x8;
typedef __attribute__((ext_vector_type(4))) float f32x4;

__device__ __forceinline__ float feat(float x) {
    // elu(x) + 1 == x+1 (x>0), exp(x) (x<=0)
    return x > 0.0f ? (x + 1.0f) : __expf(x);
}

__device__ __forceinline__ uint32_t bf16bits(float x) {
    __hip_bfloat16 h = __float2bfloat16(x);   // RNE
    return (uint32_t)*reinterpret_cast<unsigned short*>(&h);
}

// s-octet XOR swizzle: octet o of row r lives at octet (o ^ ((r>>2)&3)).
// Staging u32 writes drop from ~8-way to ~2-way bank conflict; fragment
// b128 reads stay <=2-way (free). Bijective per row, pad octet untouched.
__device__ __forceinline__ int swz_col(int row, int oct, int within) {
    return ((oct ^ ((row >> 2) & 3)) << 3) + within;
}

// One block per (bn, chunk). 256 threads = 4 waves; wave w owns the 32x32
// output quadrant (wm, wd) of Sst[64][64]. LDS tiles stored transposed
// (Kl[d][s], Vl[m][s], bf16) so each MFMA fragment is one ds_read_b128.
// Single-barrier double-buffered pipeline: stage buf[t&1], issue loads for
// tile t+1, barrier, MFMA buf[t&1].
__global__ __launch_bounds__(256, 8)
void rcla_partial(const float* __restrict__ key,
                  const float* __restrict__ value,
                  const int* __restrict__ mask,
                  float* __restrict__ ws, int C) {
    const int blk = blockIdx.x;
    const int c  = blk % C;
    const int bn = blk / C;
    const int b  = bn >> 4;   // N = 16
    const int n  = bn & 15;
    const int t  = threadIdx.x;

    // staging mapping: thread t handles columns c0..c0+3 of rows sl, sl+1
    const int a  = t & 15;
    const int p  = t >> 4;        // 0..15
    const int c0 = a << 2;        // d (K) / m (V)
    const int sl = p << 1;        // local s (even)

    // MFMA mapping
    const int lane = t & 63;
    const int w    = t >> 6;
    const int wm   = (w >> 1) << 5;
    const int wd   = (w & 1) << 5;
    const int g    = lane >> 4;   // s-octet of the fragment
    const int lr   = lane & 15;

    __shared__ __hip_bfloat16 Kl[2][DD][PAD];   // 10240 B
    __shared__ __hip_bfloat16 Vl[2][MM][PAD];   // 10240 B -> 20480 total (8 blk/CU)

    const int steps   = SS / C;   // 512 at C=16
    const int nt      = steps / TS;
    const int s_begin = c * steps;

    const float* kb = key   + (((size_t)b * SS) * NN + n) * DD + (size_t)s_begin * (NN * DD);
    const float* vb = value + (((size_t)b * SS) * NN + n) * MM + (size_t)s_begin * (NN * MM);
    const int*   mb = mask  + (size_t)b * SS + s_begin;

    // per-thread mask bits: this thread only ever touches rows sl, sl+1 of
    // each tile -> 2*nt bits total (one 32B region per wave per tile index).
    uint64_t bits = 0;
    for (int i = 0; i < nt; ++i) {
        bits |= (uint64_t)(mb[i * TS + sl]     != 0) << (2 * i);
        bits |= (uint64_t)(mb[i * TS + sl + 1] != 0) << (2 * i + 1);
    }

    f32x4 acc[2][2] = {};
    float zacc[4] = {0.f, 0.f, 0.f, 0.f};

    const float4 z4 = make_float4(0.f, 0.f, 0.f, 0.f);
    float4 kq0 = z4, kq1 = z4, vq0 = z4, vq1 = z4;
    bool lv0 = false, lv1 = false;

    #define LOADT(ti)                                                                 \
        do {                                                                          \
            lv0 = !((bits >> (2 * (ti))) & 1);                                        \
            lv1 = !((bits >> (2 * (ti) + 1)) & 1);                                    \
            kq0 = z4; kq1 = z4; vq0 = z4; vq1 = z4;                                   \
            const size_t s0 = (size_t)((ti) * TS + sl);                               \
            if (lv0) {                                                                \
                kq0 = *reinterpret_cast<const float4*>(kb + s0 * (NN * DD) + c0);     \
                vq0 = *reinterpret_cast<const float4*>(vb + s0 * (NN * MM) + c0);     \
            }                                                                         \
            if (lv1) {                                                                \
                kq1 = *reinterpret_cast<const float4*>(kb + (s0+1) * (NN * DD) + c0); \
                vq1 = *reinterpret_cast<const float4*>(vb + (s0+1) * (NN * MM) + c0); \
            }                                                                         \
        } while (0)

    LOADT(0);

    const int soct = sl >> 3;     // s-octet of this thread's staging writes
    const int swin = sl & 7;      // position within octet

    for (int ti = 0; ti < nt; ++ti) {
        const int buf = ti & 1;
        // stage tile ti (feat + cvt + swizzled LDS write) from prefetched regs
        {
            const float k0[4] = {kq0.x, kq0.y, kq0.z, kq0.w};
            const float k1[4] = {kq1.x, kq1.y, kq1.z, kq1.w};
            const float v0[4] = {vq0.x, vq0.y, vq0.z, vq0.w};
            const float v1[4] = {vq1.x, vq1.y, vq1.z, vq1.w};
            #pragma unroll
            for (int j = 0; j < 4; ++j) {
                const float fk0 = lv0 ? feat(k0[j]) : 0.f;
                const float fk1 = lv1 ? feat(k1[j]) : 0.f;
                const float fv0 = lv0 ? v0[j] : 0.f;
                const float fv1 = lv1 ? v1[j] : 0.f;
                zacc[j] += fk0 + fk1;
                const uint32_t pk = (bf16bits(fk1) << 16) | bf16bits(fk0);
                const uint32_t pv = (bf16bits(fv1) << 16) | bf16bits(fv0);
                const int row = c0 + j;
                const int col = swz_col(row, soct, swin);
                *reinterpret_cast<uint32_t*>(&Kl[buf][row][col]) = pk;
                *reinterpret_cast<uint32_t*>(&Vl[buf][row][col]) = pv;
            }
        }
        // issue next tile's predicated loads; latency hides under barrier+MFMA
        if (ti + 1 < nt) LOADT(ti + 1);

        __syncthreads();   // buf[ti&1] staged by all waves

        const int rA0 = wm + lr, rA1 = wm + 16 + lr;
        const int rB0 = wd + lr, rB1 = wd + 16 + lr;
        const bf16x8 a0 = *reinterpret_cast<const bf16x8*>(&Vl[buf][rA0][swz_col(rA0, g, 0)]);
        const bf16x8 a1 = *reinterpret_cast<const bf16x8*>(&Vl[buf][rA1][swz_col(rA1, g, 0)]);
        const bf16x8 b0 = *reinterpret_cast<const bf16x8*>(&Kl[buf][rB0][swz_col(rB0, g, 0)]);
        const bf16x8 b1 = *reinterpret_cast<const bf16x8*>(&Kl[buf][rB1][swz_col(rB1, g, 0)]);
        acc[0][0] = __builtin_amdgcn_mfma_f32_16x16x32_bf16(a0, b0, acc[0][0], 0, 0, 0);
        acc[0][1] = __builtin_amdgcn_mfma_f32_16x16x32_bf16(a0, b1, acc[0][1], 0, 0, 0);
        acc[1][0] = __builtin_amdgcn_mfma_f32_16x16x32_bf16(a1, b0, acc[1][0], 0, 0, 0);
        acc[1][1] = __builtin_amdgcn_mfma_f32_16x16x32_bf16(a1, b1, acc[1][1], 0, 0, 0);
        // no second barrier: stage(t+1) writes buf[(t+1)&1], which mfma(t)
        // does not read; stage(t+2)'s reuse of buf[t&1] is fenced by the
        // barrier of iteration t+1.
    }
    #undef LOADT

    // partials: 4096 Sst + 64 Z per (bn, c)
    float* out = ws + ((size_t)bn * C + c) * 4160;

    // C/D layout: col = lane&15, row = (lane>>4)*4 + reg
    #pragma unroll
    for (int i = 0; i < 2; ++i)
        #pragma unroll
        for (int j = 0; j < 2; ++j)
            #pragma unroll
            for (int r = 0; r < 4; ++r) {
                const int m = wm + 16 * i + g * 4 + r;
                const int d = wd + 16 * j + lr;
                out[m * DD + d] = acc[i][j][r];
            }

    // Z reduction: reuse Kl[0] as float scratch (last MFMA read buffer 1; the
    // preceding barrier fences any lagging wave's MFMA of an earlier tile).
    __syncthreads();
    float* Zf = reinterpret_cast<float*>(&Kl[0][0][0]);   // [16][64] floats
    *reinterpret_cast<float4*>(&Zf[p * DD + c0]) =
        make_float4(zacc[0], zacc[1], zacc[2], zacc[3]);
    __syncthreads();
    if (t < DD) {
        float z = 0.f;
        #pragma unroll
        for (int q = 0; q < 16; ++q) z += Zf[q * DD + t];
        out[4096 + t] = z;
    }
}

// One block per (bn, m-quarter): reduce C partials for 16 m-rows, emit Sst
// (and Z from quarter 0), then QZ and V.
__global__ __launch_bounds__(256)
void rcla_final(const float* __restrict__ query,
                const float* __restrict__ ws, int C,
                float* __restrict__ outV, float* __restrict__ outS,
                float* __restrict__ outZ) {
    const int q   = blockIdx.x & 3;
    const int bn  = blockIdx.x >> 2;
    const int t   = threadIdx.x;
    const int d0  = (t & 15) << 2;
    const int mr  = (q << 4) + (t >> 4);
    const float* p0 = ws + (size_t)bn * C * 4160;

    float sst[4] = {0.f, 0.f, 0.f, 0.f};
    float z[4]   = {0.f, 0.f, 0.f, 0.f};

    for (int c = 0; c < C; ++c) {
        const float* p = p0 + (size_t)c * 4160;
        const float4 v = *reinterpret_cast<const float4*>(p + mr * DD + d0);
        sst[0] += v.x; sst[1] += v.y; sst[2] += v.z; sst[3] += v.w;
        const float4 zv = *reinterpret_cast<const float4*>(p + 4096 + d0);
        z[0] += zv.x; z[1] += zv.y; z[2] += zv.z; z[3] += zv.w;
    }

    *reinterpret_cast<float4*>(outS + (size_t)bn * 4096 + mr * DD + d0) =
        make_float4(sst[0], sst[1], sst[2], sst[3]);
    if (q == 0 && t < 16) {
        *reinterpret_cast<float4*>(outZ + (size_t)bn * DD + d0) =
            make_float4(z[0], z[1], z[2], z[3]);
    }

    float qf[4];
    #pragma unroll
    for (int j = 0; j < 4; ++j) qf[j] = feat(query[(size_t)bn * DD + d0 + j]);

    float pd = qf[0]*z[0] + qf[1]*z[1] + qf[2]*z[2] + qf[3]*z[3];
    float pv = qf[0]*sst[0] + qf[1]*sst[1] + qf[2]*sst[2] + qf[3]*sst[3];
    #pragma unroll
    for (int off = 1; off < 16; off <<= 1) {
        pd += __shfl_xor(pd, off);
        pv += __shfl_xor(pv, off);
    }
    if ((t & 15) == 0) {
        const float qz = 1.0f / (pd + 1e-6f);
        outV[(size_t)bn * MM + mr] = qz * pv;
    }
}

extern "C" void kernel_launch(void* const* d_in, const int* in_sizes, int n_in,
                              void* d_out, int out_size, void* d_ws, size_t ws_size,
                              hipStream_t stream) {
    const float* query = (const float*)d_in[0];
    const float* key   = (const float*)d_in[1];
    const float* value = (const float*)d_in[2];
    const int*   mask  = (const int*)d_in[3];

    float* out  = (float*)d_out;
    float* outV = out;                         // [B,N,M]   8192
    float* outS = out + BB * NN * MM;          // [B,N,M,D] 524288
    float* outZ = outS + BB * NN * MM * DD;    // [B,N,D]   8192
    float* ws   = (float*)d_ws;

    int C = 16;   // 2048 blocks -> 8 blocks/CU (32 waves/CU)
    while (C > 8 && (size_t)BB * NN * C * 4160 * sizeof(float) > ws_size) C >>= 1;

    rcla_partial<<<dim3(BB * NN * C), dim3(256), 0, stream>>>(key, value, mask, ws, C);
    rcla_final<<<dim3(BB * NN * 4), dim3(256), 0, stream>>>(query, ws, C, outV, outS, outZ);
}

// Round 5
// 77.119 us; speedup vs baseline: 1.0702x; 1.0702x over previous
//
#include <hip/hip_runtime.h>
#include <hip/hip_bf16.h>
#include <stdint.h>

#define BB 8
#define SS 8192
#define NN 16
#define DD 64
#define MM 64
#define TS 32    // s-rows per LDS tile
#define PAD 40   // row stride (bf16): 80 B -> every row 16B-aligned, 4 data octets + 1 pad

typedef __attribute__((ext_vector_type(8))) short bf16x8;
typedef __attribute__((ext_vector_type(4))) float f32x4;

__device__ __forceinline__ float feat(float x) {
    // elu(x) + 1 == x+1 (x>0), exp(x) (x<=0)
    return x > 0.0f ? (x + 1.0f) : __expf(x);
}

__device__ __forceinline__ uint32_t bf16bits(float x) {
    __hip_bfloat16 h = __float2bfloat16(x);   // RNE
    return (uint32_t)*reinterpret_cast<unsigned short*>(&h);
}

// s-octet XOR swizzle: data octet o of row r lives at octet (o ^ ((r>>2)&3)).
// Staging u32 writes drop 8-way -> 4-way bank conflict; fragment b128 reads
// fetch data octet g for every row (k-order consistent across A/B), <=2-way.
__device__ __forceinline__ int swz_col(int row, int oct, int within) {
    return ((oct ^ ((row >> 2) & 3)) << 3) + within;
}

// One block per (bn, chunk). 256 threads = 4 waves; wave w owns the 32x32
// output quadrant (wm, wd) of Sst[64][64]. LDS tiles stored transposed
// (Kl[d][s], Vl[m][s], bf16) so each MFMA fragment is one ds_read_b128.
// Pipeline per tile: stage buf[ti&1] (consumes loads issued last iter) ->
// barrier (drain-free: nothing outstanding) -> issue loads for ti+1 ->
// MFMA buf[ti&1]. Loads issued AFTER the barrier so the compiler's
// vmcnt(0)-before-s_barrier drain never serializes HBM latency.
__global__ __launch_bounds__(256)
void rcla_partial(const float* __restrict__ key,
                  const float* __restrict__ value,
                  const int* __restrict__ mask,
                  float* __restrict__ ws, int C) {
    const int blk = blockIdx.x;
    const int c  = blk % C;
    const int bn = blk / C;
    const int b  = bn >> 4;   // N = 16
    const int n  = bn & 15;
    const int t  = threadIdx.x;

    // staging mapping: thread t handles columns c0..c0+3 of rows sl, sl+1
    const int a  = t & 15;
    const int p  = t >> 4;        // 0..15
    const int c0 = a << 2;        // d (K) / m (V)
    const int sl = p << 1;        // local s (even)

    // MFMA mapping
    const int lane = t & 63;
    const int w    = t >> 6;
    const int wm   = (w >> 1) << 5;
    const int wd   = (w & 1) << 5;
    const int g    = lane >> 4;   // s-octet of the fragment
    const int lr   = lane & 15;

    __shared__ __align__(16) __hip_bfloat16 Kl[2][DD][PAD];   // 10240 B
    __shared__ __align__(16) __hip_bfloat16 Vl[2][MM][PAD];   // 10240 B -> 20480 total

    const int steps   = SS / C;   // 512 at C=16
    const int nt      = steps / TS;
    const int s_begin = c * steps;

    const float* kb = key   + (((size_t)b * SS) * NN + n) * DD + (size_t)s_begin * (NN * DD);
    const float* vb = value + (((size_t)b * SS) * NN + n) * MM + (size_t)s_begin * (NN * MM);
    const int*   mb = mask  + (size_t)b * SS + s_begin;

    // per-thread mask bits: this thread only ever touches rows sl, sl+1 of
    // each tile -> 2*nt bits total (<=64 for C>=8).
    uint64_t bits = 0;
    for (int i = 0; i < nt; ++i) {
        bits |= (uint64_t)(mb[i * TS + sl]     != 0) << (2 * i);
        bits |= (uint64_t)(mb[i * TS + sl + 1] != 0) << (2 * i + 1);
    }

    f32x4 acc[2][2] = {};
    float zacc[4] = {0.f, 0.f, 0.f, 0.f};

    const float4 z4 = make_float4(0.f, 0.f, 0.f, 0.f);
    float4 kq0 = z4, kq1 = z4, vq0 = z4, vq1 = z4;
    bool lv0 = false, lv1 = false;

    #define LOADT(ti)                                                                 \
        do {                                                                          \
            lv0 = !((bits >> (2 * (ti))) & 1);                                        \
            lv1 = !((bits >> (2 * (ti) + 1)) & 1);                                    \
            kq0 = z4; kq1 = z4; vq0 = z4; vq1 = z4;                                   \
            const size_t s0 = (size_t)((ti) * TS + sl);                               \
            if (lv0) {                                                                \
                kq0 = *reinterpret_cast<const float4*>(kb + s0 * (NN * DD) + c0);     \
                vq0 = *reinterpret_cast<const float4*>(vb + s0 * (NN * MM) + c0);     \
            }                                                                         \
            if (lv1) {                                                                \
                kq1 = *reinterpret_cast<const float4*>(kb + (s0+1) * (NN * DD) + c0); \
                vq1 = *reinterpret_cast<const float4*>(vb + (s0+1) * (NN * MM) + c0); \
            }                                                                         \
        } while (0)

    LOADT(0);

    const int soct = sl >> 3;     // s-octet of this thread's staging writes
    const int swin = sl & 7;      // position within octet

    for (int ti = 0; ti < nt; ++ti) {
        const int buf = ti & 1;
        // stage tile ti (feat + cvt + swizzled LDS write) from prefetched regs
        {
            const float k0[4] = {kq0.x, kq0.y, kq0.z, kq0.w};
            const float k1[4] = {kq1.x, kq1.y, kq1.z, kq1.w};
            const float v0[4] = {vq0.x, vq0.y, vq0.z, vq0.w};
            const float v1[4] = {vq1.x, vq1.y, vq1.z, vq1.w};
            #pragma unroll
            for (int j = 0; j < 4; ++j) {
                const float fk0 = lv0 ? feat(k0[j]) : 0.f;
                const float fk1 = lv1 ? feat(k1[j]) : 0.f;
                const float fv0 = lv0 ? v0[j] : 0.f;
                const float fv1 = lv1 ? v1[j] : 0.f;
                zacc[j] += fk0 + fk1;
                const uint32_t pk = (bf16bits(fk1) << 16) | bf16bits(fk0);
                const uint32_t pv = (bf16bits(fv1) << 16) | bf16bits(fv0);
                const int row = c0 + j;
                const int col = swz_col(row, soct, swin);
                *reinterpret_cast<uint32_t*>(&Kl[buf][row][col]) = pk;
                *reinterpret_cast<uint32_t*>(&Vl[buf][row][col]) = pv;
            }
        }

        __syncthreads();   // drain-free: stage already consumed all loads

        // issue next tile's loads NOW — they stay in flight through the MFMA
        // phase and the next stage's feat/cvt, never crossing a barrier.
        if (ti + 1 < nt) LOADT(ti + 1);

        const int rA0 = wm + lr, rA1 = wm + 16 + lr;
        const int rB0 = wd + lr, rB1 = wd + 16 + lr;
        const bf16x8 a0 = *reinterpret_cast<const bf16x8*>(&Vl[buf][rA0][swz_col(rA0, g, 0)]);
        const bf16x8 a1 = *reinterpret_cast<const bf16x8*>(&Vl[buf][rA1][swz_col(rA1, g, 0)]);
        const bf16x8 b0 = *reinterpret_cast<const bf16x8*>(&Kl[buf][rB0][swz_col(rB0, g, 0)]);
        const bf16x8 b1 = *reinterpret_cast<const bf16x8*>(&Kl[buf][rB1][swz_col(rB1, g, 0)]);
        acc[0][0] = __builtin_amdgcn_mfma_f32_16x16x32_bf16(a0, b0, acc[0][0], 0, 0, 0);
        acc[0][1] = __builtin_amdgcn_mfma_f32_16x16x32_bf16(a0, b1, acc[0][1], 0, 0, 0);
        acc[1][0] = __builtin_amdgcn_mfma_f32_16x16x32_bf16(a1, b0, acc[1][0], 0, 0, 0);
        acc[1][1] = __builtin_amdgcn_mfma_f32_16x16x32_bf16(a1, b1, acc[1][1], 0, 0, 0);
        // single barrier per tile: stage(ti+1) writes buf[(ti+1)&1] (not read
        // by mfma(ti)); stage(ti+2)'s reuse of buf[ti&1] is fenced by the
        // barrier of iteration ti+1.
    }
    #undef LOADT

    // partials: 4096 Sst + 64 Z per (bn, c)
    float* out = ws + ((size_t)bn * C + c) * 4160;

    // C/D layout: col = lane&15, row = (lane>>4)*4 + reg
    #pragma unroll
    for (int i = 0; i < 2; ++i)
        #pragma unroll
        for (int j = 0; j < 2; ++j)
            #pragma unroll
            for (int r = 0; r < 4; ++r) {
                const int m = wm + 16 * i + g * 4 + r;
                const int d = wd + 16 * j + lr;
                out[m * DD + d] = acc[i][j][r];
            }

    // Z reduction: reuse Kl[0] as float scratch (all MFMA reads of Kl are
    // fenced by the barrier below).
    __syncthreads();
    float* Zf = reinterpret_cast<float*>(&Kl[0][0][0]);   // [16][64] floats
    *reinterpret_cast<float4*>(&Zf[p * DD + c0]) =
        make_float4(zacc[0], zacc[1], zacc[2], zacc[3]);
    __syncthreads();
    if (t < DD) {
        float z = 0.f;
        #pragma unroll
        for (int q = 0; q < 16; ++q) z += Zf[q * DD + t];
        out[4096 + t] = z;
    }
}

// One block per (bn, m-quarter): reduce C partials for 16 m-rows, emit Sst
// (and Z from quarter 0), then QZ and V.
__global__ __launch_bounds__(256)
void rcla_final(const float* __restrict__ query,
                const float* __restrict__ ws, int C,
                float* __restrict__ outV, float* __restrict__ outS,
                float* __restrict__ outZ) {
    const int q   = blockIdx.x & 3;
    const int bn  = blockIdx.x >> 2;
    const int t   = threadIdx.x;
    const int d0  = (t & 15) << 2;
    const int mr  = (q << 4) + (t >> 4);
    const float* p0 = ws + (size_t)bn * C * 4160;

    float sst[4] = {0.f, 0.f, 0.f, 0.f};
    float z[4]   = {0.f, 0.f, 0.f, 0.f};

    for (int c = 0; c < C; ++c) {
        const float* p = p0 + (size_t)c * 4160;
        const float4 v = *reinterpret_cast<const float4*>(p + mr * DD + d0);
        sst[0] += v.x; sst[1] += v.y; sst[2] += v.z; sst[3] += v.w;
        const float4 zv = *reinterpret_cast<const float4*>(p + 4096 + d0);
        z[0] += zv.x; z[1] += zv.y; z[2] += zv.z; z[3] += zv.w;
    }

    *reinterpret_cast<float4*>(outS + (size_t)bn * 4096 + mr * DD + d0) =
        make_float4(sst[0], sst[1], sst[2], sst[3]);
    if (q == 0 && t < 16) {
        *reinterpret_cast<float4*>(outZ + (size_t)bn * DD + d0) =
            make_float4(z[0], z[1], z[2], z[3]);
    }

    float qf[4];
    #pragma unroll
    for (int j = 0; j < 4; ++j) qf[j] = feat(query[(size_t)bn * DD + d0 + j]);

    float pd = qf[0]*z[0] + qf[1]*z[1] + qf[2]*z[2] + qf[3]*z[3];
    float pv = qf[0]*sst[0] + qf[1]*sst[1] + qf[2]*sst[2] + qf[3]*sst[3];
    #pragma unroll
    for (int off = 1; off < 16; off <<= 1) {
        pd += __shfl_xor(pd, off);
        pv += __shfl_xor(pv, off);
    }
    if ((t & 15) == 0) {
        const float qz = 1.0f / (pd + 1e-6f);
        outV[(size_t)bn * MM + mr] = qz * pv;
    }
}

extern "C" void kernel_launch(void* const* d_in, const int* in_sizes, int n_in,
                              void* d_out, int out_size, void* d_ws, size_t ws_size,
                              hipStream_t stream) {
    const float* query = (const float*)d_in[0];
    const float* key   = (const float*)d_in[1];
    const float* value = (const float*)d_in[2];
    const int*   mask  = (const int*)d_in[3];

    float* out  = (float*)d_out;
    float* outV = out;                         // [B,N,M]   8192
    float* outS = out + BB * NN * MM;          // [B,N,M,D] 524288
    float* outZ = outS + BB * NN * MM * DD;    // [B,N,D]   8192
    float* ws   = (float*)d_ws;

    int C = 16;   // 2048 blocks -> 8 blocks/CU (32 waves/CU)
    while (C > 8 && (size_t)BB * NN * C * 4160 * sizeof(float) > ws_size) C >>= 1;

    rcla_partial<<<dim3(BB * NN * C), dim3(256), 0, stream>>>(key, value, mask, ws, C);
    rcla_final<<<dim3(BB * NN * 4), dim3(256), 0, stream>>>(query, ws, C, outV, outS, outZ);
}

// Round 7
// 71.009 us; speedup vs baseline: 1.1623x; 1.0860x over previous
//
#include <hip/hip_runtime.h>
#include <hip/hip_bf16.h>
#include <stdint.h>

#define BB 8
#define SS 8192
#define NN 16
#define DD 64
#define MM 64
#define TS 32    // s-rows per LDS tile
#define PAD 40   // row stride (bf16): 80 B, 16B-aligned rows; reads 2-way (free), writes 8-way (accepted)

typedef __attribute__((ext_vector_type(8))) short bf16x8;
typedef __attribute__((ext_vector_type(4))) float f32x4;

__device__ __forceinline__ float feat(float x) {
    // elu(x) + 1 == x+1 (x>0), exp(x) (x<=0)
    return x > 0.0f ? (x + 1.0f) : __expf(x);
}

__device__ __forceinline__ uint32_t bf16bits(float x) {
    __hip_bfloat16 h = __float2bfloat16(x);   // RNE
    return (uint32_t)*reinterpret_cast<unsigned short*>(&h);
}

// Raw barrier (no vmcnt drain): sched_barrier pins LDS ops above, the
// explicit lgkmcnt(0) makes this wave's ds_writes visible, s_barrier syncs
// arrival. Global loads issued earlier stay IN FLIGHT across it (T4).
#define SYNCW()                                        \
    do {                                               \
        __builtin_amdgcn_sched_barrier(0);             \
        asm volatile("s_waitcnt lgkmcnt(0)");          \
        __builtin_amdgcn_s_barrier();                  \
        __builtin_amdgcn_sched_barrier(0);             \
    } while (0)

struct Slot {
    float4 kq0, kq1, vq0, vq1;
    bool lv0, lv1;
};

__device__ __forceinline__ void load_tile(Slot& s, int ti, uint32_t bits,
                                          const float* kb, const float* vb,
                                          int sl, int c0) {
    const float4 z4 = make_float4(0.f, 0.f, 0.f, 0.f);
    s.lv0 = !((bits >> (2 * ti)) & 1);
    s.lv1 = !((bits >> (2 * ti + 1)) & 1);
    s.kq0 = z4; s.kq1 = z4; s.vq0 = z4; s.vq1 = z4;
    const size_t s0 = (size_t)(ti * TS + sl);
    if (s.lv0) {
        s.kq0 = *reinterpret_cast<const float4*>(kb + s0 * (NN * DD) + c0);
        s.vq0 = *reinterpret_cast<const float4*>(vb + s0 * (NN * MM) + c0);
    }
    if (s.lv1) {
        s.kq1 = *reinterpret_cast<const float4*>(kb + (s0 + 1) * (NN * DD) + c0);
        s.vq1 = *reinterpret_cast<const float4*>(vb + (s0 + 1) * (NN * MM) + c0);
    }
}

__device__ __forceinline__ void stage_tile(const Slot& s, float* zacc,
                                           __hip_bfloat16 (*Kbuf)[PAD],
                                           __hip_bfloat16 (*Vbuf)[PAD],
                                           int c0, int sl) {
    const float sk0[4] = {s.kq0.x, s.kq0.y, s.kq0.z, s.kq0.w};
    const float sk1[4] = {s.kq1.x, s.kq1.y, s.kq1.z, s.kq1.w};
    const float sv0[4] = {s.vq0.x, s.vq0.y, s.vq0.z, s.vq0.w};
    const float sv1[4] = {s.vq1.x, s.vq1.y, s.vq1.z, s.vq1.w};
    #pragma unroll
    for (int j = 0; j < 4; ++j) {
        const float fk0 = s.lv0 ? feat(sk0[j]) : 0.f;
        const float fk1 = s.lv1 ? feat(sk1[j]) : 0.f;
        const float fv0 = s.lv0 ? sv0[j] : 0.f;
        const float fv1 = s.lv1 ? sv1[j] : 0.f;
        zacc[j] += fk0 + fk1;
        const uint32_t pk = (bf16bits(fk1) << 16) | bf16bits(fk0);
        const uint32_t pv = (bf16bits(fv1) << 16) | bf16bits(fv0);
        *reinterpret_cast<uint32_t*>(&Kbuf[c0 + j][sl]) = pk;
        *reinterpret_cast<uint32_t*>(&Vbuf[c0 + j][sl]) = pv;
    }
}

__device__ __forceinline__ void mfma_step(const __hip_bfloat16 (*Kbuf)[PAD],
                                          const __hip_bfloat16 (*Vbuf)[PAD],
                                          f32x4& acc00, f32x4& acc01,
                                          f32x4& acc10, f32x4& acc11,
                                          int wm, int wd, int g, int lr) {
    const bf16x8 fa0 = *reinterpret_cast<const bf16x8*>(&Vbuf[wm + lr][g * 8]);
    const bf16x8 fa1 = *reinterpret_cast<const bf16x8*>(&Vbuf[wm + 16 + lr][g * 8]);
    const bf16x8 fb0 = *reinterpret_cast<const bf16x8*>(&Kbuf[wd + lr][g * 8]);
    const bf16x8 fb1 = *reinterpret_cast<const bf16x8*>(&Kbuf[wd + 16 + lr][g * 8]);
    acc00 = __builtin_amdgcn_mfma_f32_16x16x32_bf16(fa0, fb0, acc00, 0, 0, 0);
    acc01 = __builtin_amdgcn_mfma_f32_16x16x32_bf16(fa0, fb1, acc01, 0, 0, 0);
    acc10 = __builtin_amdgcn_mfma_f32_16x16x32_bf16(fa1, fb0, acc10, 0, 0, 0);
    acc11 = __builtin_amdgcn_mfma_f32_16x16x32_bf16(fa1, fb1, acc11, 0, 0, 0);
}

// One block per (bn, chunk). 256 threads = 4 waves; wave w owns the 32x32
// output quadrant (wm, wd) of Sst[64][64]. LDS tiles stored transposed
// (Kl[d][s], Vl[m][s], bf16) so each MFMA fragment is one ds_read_b128.
// Pipeline: depth-2 register prefetch (slots sA/sB) + double-buffered LDS +
// ONE raw barrier per tile. load(ti+2) is issued ~2 full phases (~700 cy)
// before consumption -> HBM latency hidden; no barrier ever drains vmcnt.
__global__ __launch_bounds__(256)
void rcla_partial(const float* __restrict__ key,
                  const float* __restrict__ value,
                  const int* __restrict__ mask,
                  float* __restrict__ ws, int C) {
    const int blk = blockIdx.x;
    const int c  = blk % C;
    const int bn = blk / C;
    const int b  = bn >> 4;   // N = 16
    const int n  = bn & 15;
    const int t  = threadIdx.x;

    // staging mapping: thread t handles columns c0..c0+3 of rows sl, sl+1
    const int a  = t & 15;
    const int p  = t >> 4;        // 0..15
    const int c0 = a << 2;        // d (K) / m (V)
    const int sl = p << 1;        // local s (even)

    // MFMA mapping
    const int lane = t & 63;
    const int w    = t >> 6;
    const int wm   = (w >> 1) << 5;
    const int wd   = (w & 1) << 5;
    const int g    = lane >> 4;   // s-octet of the fragment
    const int lr   = lane & 15;

    __shared__ __align__(16) __hip_bfloat16 Kl[2][DD][PAD];   // 10240 B
    __shared__ __align__(16) __hip_bfloat16 Vl[2][MM][PAD];   // 10240 B -> 20480 total

    const int steps   = SS / C;      // 512 at C=16
    const int nt      = steps / TS;  // 16 (even; 2*nt <= 32 bits)
    const int s_begin = c * steps;

    const float* kb = key   + (((size_t)b * SS) * NN + n) * DD + (size_t)s_begin * (NN * DD);
    const float* vb = value + (((size_t)b * SS) * NN + n) * MM + (size_t)s_begin * (NN * MM);
    const int*   mb = mask  + (size_t)b * SS + s_begin;

    // per-thread mask bits: this thread only ever touches rows sl, sl+1
    uint32_t bits = 0;
    for (int i = 0; i < nt; ++i) {
        bits |= (uint32_t)(mb[i * TS + sl]     != 0) << (2 * i);
        bits |= (uint32_t)(mb[i * TS + sl + 1] != 0) << (2 * i + 1);
    }

    f32x4 acc00 = {}, acc01 = {}, acc10 = {}, acc11 = {};
    float zacc[4] = {0.f, 0.f, 0.f, 0.f};

    Slot sA, sB;
    load_tile(sA, 0, bits, kb, vb, sl, c0);
    load_tile(sB, 1, bits, kb, vb, sl, c0);

    // Hazard ledger (1 barrier/tile): every LDS write-after-read pair
    // (stage_tile(x, buf) vs previous mfma_step(buf)) is separated by
    // exactly one SYNCW arrival barrier; all LDS ops are lgkm-waited
    // before barrier entry.
    for (int ti = 0; ti < nt; ti += 2) {
        stage_tile(sA, zacc, Kl[0], Vl[0], c0, sl);
        if (ti + 2 < nt) load_tile(sA, ti + 2, bits, kb, vb, sl, c0);
        SYNCW();
        mfma_step(Kl[0], Vl[0], acc00, acc01, acc10, acc11, wm, wd, g, lr);

        stage_tile(sB, zacc, Kl[1], Vl[1], c0, sl);
        if (ti + 3 < nt) load_tile(sB, ti + 3, bits, kb, vb, sl, c0);
        SYNCW();
        mfma_step(Kl[1], Vl[1], acc00, acc01, acc10, acc11, wm, wd, g, lr);
    }

    // partials: 4096 Sst + 64 Z per (bn, c)
    float* out = ws + ((size_t)bn * C + c) * 4160;

    // C/D layout: col = lane&15, row = (lane>>4)*4 + reg
    #pragma unroll
    for (int r = 0; r < 4; ++r) {
        out[(wm + g * 4 + r) * DD + wd + lr]           = acc00[r];
        out[(wm + g * 4 + r) * DD + wd + 16 + lr]      = acc01[r];
        out[(wm + 16 + g * 4 + r) * DD + wd + lr]      = acc10[r];
        out[(wm + 16 + g * 4 + r) * DD + wd + 16 + lr] = acc11[r];
    }

    // Z reduction: reuse Kl[0] as float scratch (fenced by __syncthreads).
    __syncthreads();
    float* Zf = reinterpret_cast<float*>(&Kl[0][0][0]);   // [16][64] floats
    *reinterpret_cast<float4*>(&Zf[p * DD + c0]) =
        make_float4(zacc[0], zacc[1], zacc[2], zacc[3]);
    __syncthreads();
    if (t < DD) {
        float z = 0.f;
        #pragma unroll
        for (int q = 0; q < 16; ++q) z += Zf[q * DD + t];
        out[4096 + t] = z;
    }
}

// One block per (bn, m-quarter): reduce C partials for 16 m-rows, emit Sst
// (and Z from quarter 0), then QZ and V.
__global__ __launch_bounds__(256)
void rcla_final(const float* __restrict__ query,
                const float* __restrict__ ws, int C,
                float* __restrict__ outV, float* __restrict__ outS,
                float* __restrict__ outZ) {
    const int q   = blockIdx.x & 3;
    const int bn  = blockIdx.x >> 2;
    const int t   = threadIdx.x;
    const int d0  = (t & 15) << 2;
    const int mr  = (q << 4) + (t >> 4);
    const float* p0 = ws + (size_t)bn * C * 4160;

    float sst[4] = {0.f, 0.f, 0.f, 0.f};
    float z[4]   = {0.f, 0.f, 0.f, 0.f};

    for (int c = 0; c < C; ++c) {
        const float* p = p0 + (size_t)c * 4160;
        const float4 v = *reinterpret_cast<const float4*>(p + mr * DD + d0);
        sst[0] += v.x; sst[1] += v.y; sst[2] += v.z; sst[3] += v.w;
        const float4 zv = *reinterpret_cast<const float4*>(p + 4096 + d0);
        z[0] += zv.x; z[1] += zv.y; z[2] += zv.z; z[3] += zv.w;
    }

    *reinterpret_cast<float4*>(outS + (size_t)bn * 4096 + mr * DD + d0) =
        make_float4(sst[0], sst[1], sst[2], sst[3]);
    if (q == 0 && t < 16) {
        *reinterpret_cast<float4*>(outZ + (size_t)bn * DD + d0) =
            make_float4(z[0], z[1], z[2], z[3]);
    }

    float qf[4];
    #pragma unroll
    for (int j = 0; j < 4; ++j) qf[j] = feat(query[(size_t)bn * DD + d0 + j]);

    float pd = qf[0]*z[0] + qf[1]*z[1] + qf[2]*z[2] + qf[3]*z[3];
    float pv = qf[0]*sst[0] + qf[1]*sst[1] + qf[2]*sst[2] + qf[3]*sst[3];
    #pragma unroll
    for (int off = 1; off < 16; off <<= 1) {
        pd += __shfl_xor(pd, off);
        pv += __shfl_xor(pv, off);
    }
    if ((t & 15) == 0) {
        const float qz = 1.0f / (pd + 1e-6f);
        outV[(size_t)bn * MM + mr] = qz * pv;
    }
}

extern "C" void kernel_launch(void* const* d_in, const int* in_sizes, int n_in,
                              void* d_out, int out_size, void* d_ws, size_t ws_size,
                              hipStream_t stream) {
    const float* query = (const float*)d_in[0];
    const float* key   = (const float*)d_in[1];
    const float* value = (const float*)d_in[2];
    const int*   mask  = (const int*)d_in[3];

    float* out  = (float*)d_out;
    float* outV = out;                         // [B,N,M]   8192
    float* outS = out + BB * NN * MM;          // [B,N,M,D] 524288
    float* outZ = outS + BB * NN * MM * DD;    // [B,N,D]   8192
    float* ws   = (float*)d_ws;

    int C = 16;   // 2048 blocks -> 8 blocks/CU (32 waves/CU)
    while (C > 8 && (size_t)BB * NN * C * 4160 * sizeof(float) > ws_size) C >>= 1;

    rcla_partial<<<dim3(BB * NN * C), dim3(256), 0, stream>>>(key, value, mask, ws, C);
    rcla_final<<<dim3(BB * NN * 4), dim3(256), 0, stream>>>(query, ws, C, outV, outS, outZ);
}